// Round 11
// baseline (104.074 us; speedup 1.0000x reference)
//
#include <hip/hip_runtime.h>

#define LSEQ 8194

typedef _Float16 f16x8 __attribute__((ext_vector_type(8)));
typedef _Float16 f16x2 __attribute__((ext_vector_type(2)));
typedef __attribute__((ext_vector_type(4))) float f32x4;

static __device__ __forceinline__ float tanh_fast(float x){
    float p = __expf(2.0f * x);
    float r = __builtin_amdgcn_rcpf(1.0f + p);
    return 1.0f - 2.0f * r;
}
// sum 3 packed-f16x2 taps + relu (v_pk_add_f16 + v_pk_max_f16)
static __device__ __forceinline__ unsigned h3relu(unsigned a, unsigned b, unsigned c){
    union { f16x2 h; unsigned u; } x, y, z, r;
    x.u = a; y.u = b; z.u = c;
    f16x2 s = x.h + y.h + z.h;
    f16x2 zero = { (_Float16)0.0f, (_Float16)0.0f };
    r.h = __builtin_elementwise_max(s, zero);
    return r.u;
}
static __device__ __forceinline__ unsigned hpack(float a, float b){
    union { f16x2 h; unsigned u; } pk;
    pk.h = (f16x2){ (_Float16)a, (_Float16)b };
    return pk.u;
}
// FUSED cross-lane add: one v_add_f32_dpp = row_ror(x) + x (vs the builtin's
// mov_dpp + add). s_nop 1 covers the VALU-write -> DPP-read hazard (inline
// asm bypasses the compiler's hazard recognizer). Operation sequence is
// identical to the R8/R9-validated rotate-reduce -> bit-identical results.
#define ROR_ADD(x, rorstr) ({ \
    float _r; \
    asm("s_nop 1\n\t" \
        "v_add_f32_dpp %0, %1, %1 " rorstr " row_mask:0xf bank_mask:0xf" \
        : "=v"(_r) : "v"(x)); \
    _r; })

// K_SETUP (= R10): stride-84 tap table (21 dwords/row, gcd(21,32)=1 -> row
// starts cycle all 32 banks; SQ_LDS_BANK_CONFLICT measured 0) + Wa f16 image
// in fragment order: uint4 (dt*4+ki)*64+lane = words (dt*16+m)*64+ki*16+q*4+j.
__global__ __launch_bounds__(256) void k_setup(
        const float* __restrict__ emb, const float* __restrict__ cw,
        const float* __restrict__ cb, const float* __restrict__ Wa,
        unsigned* __restrict__ tblG, unsigned* __restrict__ wahG)
{
    int gid = blockIdx.x*256 + threadIdx.x;
    if (gid < 1248){
        int k = gid / 416;          // 416 = 26*16
        int rem = gid - k*416;
        int l = rem >> 4;
        int cp = rem & 15;
        int c0 = cp*2;
        float v0 = 0.f, v1 = 0.f;
        #pragma unroll
        for (int i = 0; i < 5; i++){
            float e = emb[l*5 + i];
            v0 += cw[(c0*5 + i)*3 + k] * e;
            v1 += cw[((c0+1)*5 + i)*3 + k] * e;
        }
        if (k == 2){ v0 += cb[c0]; v1 += cb[c0+1]; }
        tblG[k*546 + l*21 + (cp & 3)*4 + (cp >> 2)] = hpack(v0, v1);  // 546=26*21
    }
    // zero-fill row pads so the LDS copy moves defined data
    if (gid >= 1248 && gid < 1248 + 390){
        int pg = gid - 1248;            // 390 = 78 rows * 5 pads
        int row = pg / 5, pw = pg - row*5;
        tblG[row*21 + 16 + pw] = 0u;
    }
    if (gid < 8) tblG[1638 + gid] = 0u;
    for (int u = gid; u < 2048; u += 1280){
        int lane = u & 63, dtki = u >> 6;
        int dt = dtki >> 2, ki = dtki & 3;
        int m = lane & 15, q = lane >> 4;
        const float2* src = (const float2*)Wa + ((dt*16 + m)*64 + ki*16 + q*4);
        float2 s0 = src[0], s1 = src[1], s2 = src[2], s3 = src[3];
        uint4 o;
        o.x = hpack(s0.x, s0.y);
        o.y = hpack(s1.x, s1.y);
        o.z = hpack(s2.x, s2.y);
        o.w = hpack(s3.x, s3.y);
        ((uint4*)wahG)[u] = o;
    }
}

// K_FUSED v12 = R9's schedule (batched af[8] per kp — best total 93.4us)
// + stride-84 table (R10: conflicts 0) + fused v_add_f32_dpp reduce.
// R10 post-mortem: the af[2][4] manual double-buffer regressed (VGPR 64,
// AGPR shuffling, 39.9us) — manual load pipelining has failed twice (R2,
// R10); the compiler's batched schedule wins. Reverted exactly.
// ki-ascending accumulation, same taps/packs/ep/pool order -> bit-identical.
__global__ __launch_bounds__(256, 2) void k_fused(
        const int* __restrict__ seq, const unsigned* __restrict__ tblG,
        const unsigned* __restrict__ wahG, const float* __restrict__ va,
        float* __restrict__ part, float* __restrict__ stats)
{
    __shared__ __align__(16) unsigned tblH[1648];      // 6592 B tap table (84B rows)
    __shared__ unsigned short seqw16[4][132];          // pre-scaled offsets (x84)
    __shared__ __align__(16) float vaL[128];

    int tid = threadIdx.x;
    int b   = blockIdx.y;
    int x   = blockIdx.x;
    int n0  = x * 128;

    // ---- prologue: small copies (one barrier) ----
    for (int i = tid; i < 412; i += 256)
        ((uint4*)tblH)[i] = ((const uint4*)tblG)[i];
    if (tid < 128) vaL[tid] = va[tid];
    const int* sb = seq + (size_t)b * LSEQ;
    for (int i = tid; i < 4*132; i += 256){
        int s = i / 132, off = i - s*132;
        if (off < 130)
            seqw16[s][off] = (unsigned short)(sb[s*2048 + n0 + off] * 84);
    }
    __syncthreads();   // the ONLY barrier

    int w = tid >> 6, lane = tid & 63;
    int m = lane & 15, q = lane >> 4;
    const char* tb0 = (const char*)tblH + q*16;
    const char* tb1 = tb0 + 2184;                      // 546 dwords per section
    const char* tb2 = tb1 + 2184;
    const uint4* wa4 = (const uint4*)wahG + lane;      // lane-contiguous frags

    // ---- gen BOTH tiles' B-frags (V scratch dies per scope) ----
    uint4 vfr0[4], vfr1[4];
    {
        int base = w*32 + m;
        unsigned V[4][4];
        #pragma unroll
        for (int s = 0; s < 4; s++){
            unsigned oa = seqw16[s][base];
            unsigned ob = seqw16[s][base+1];
            unsigned oc = seqw16[s][base+2];
            uint4 t0 = *(const uint4*)(tb0 + oa);
            uint4 t1 = *(const uint4*)(tb1 + ob);
            uint4 t2 = *(const uint4*)(tb2 + oc);
            V[s][0] = h3relu(t0.x, t1.x, t2.x);
            V[s][1] = h3relu(t0.y, t1.y, t2.y);
            V[s][2] = h3relu(t0.z, t1.z, t2.z);
            V[s][3] = h3relu(t0.w, t1.w, t2.w);
        }
        #pragma unroll
        for (int ki = 0; ki < 4; ki++){
            uint4 o;
            o.x = __builtin_amdgcn_perm(V[1][ki], V[0][ki], 0x05040100u);
            o.y = __builtin_amdgcn_perm(V[3][ki], V[2][ki], 0x05040100u);
            o.z = __builtin_amdgcn_perm(V[1][ki], V[0][ki], 0x07060302u);
            o.w = __builtin_amdgcn_perm(V[3][ki], V[2][ki], 0x07060302u);
            vfr0[ki] = o;
        }
    }
    {
        int base = w*32 + 16 + m;
        unsigned V[4][4];
        #pragma unroll
        for (int s = 0; s < 4; s++){
            unsigned oa = seqw16[s][base];
            unsigned ob = seqw16[s][base+1];
            unsigned oc = seqw16[s][base+2];
            uint4 t0 = *(const uint4*)(tb0 + oa);
            uint4 t1 = *(const uint4*)(tb1 + ob);
            uint4 t2 = *(const uint4*)(tb2 + oc);
            V[s][0] = h3relu(t0.x, t1.x, t2.x);
            V[s][1] = h3relu(t0.y, t1.y, t2.y);
            V[s][2] = h3relu(t0.z, t1.z, t2.z);
            V[s][3] = h3relu(t0.w, t1.w, t2.w);
        }
        #pragma unroll
        for (int ki = 0; ki < 4; ki++){
            uint4 o;
            o.x = __builtin_amdgcn_perm(V[1][ki], V[0][ki], 0x05040100u);
            o.y = __builtin_amdgcn_perm(V[3][ki], V[2][ki], 0x05040100u);
            o.z = __builtin_amdgcn_perm(V[1][ki], V[0][ki], 0x07060302u);
            o.w = __builtin_amdgcn_perm(V[3][ki], V[2][ki], 0x07060302u);
            vfr1[ki] = o;
        }
    }

    // ---- MFMA: 2 halves x 2 ki-pairs; per batch 8 coalesced A-loads feed
    //      16 MFMAs (both tiles). acc accumulation order stays ki-ascending.
    float ep0 = 0.f, ep1 = 0.f;
    #pragma unroll
    for (int h = 0; h < 2; h++){
        f32x4 acc0[4], acc1[4];
        #pragma unroll
        for (int dd = 0; dd < 4; dd++){
            acc0[dd] = (f32x4){0.f, 0.f, 0.f, 0.f};
            acc1[dd] = (f32x4){0.f, 0.f, 0.f, 0.f};
        }
        #pragma unroll
        for (int kp = 0; kp < 2; kp++){
            uint4 af[8];                 // [kk*4+dd], kk = ki-kp*2
            #pragma unroll
            for (int kk = 0; kk < 2; kk++)
                #pragma unroll
                for (int dd = 0; dd < 4; dd++){
                    int dt = h*4 + dd, ki = kp*2 + kk;
                    af[kk*4+dd] = wa4[(dt*4 + ki) << 6];
                }
            #pragma unroll
            for (int kk = 0; kk < 2; kk++){
                int ki = kp*2 + kk;
                union { uint4 u; f16x8 f; } b0, b1;
                b0.u = vfr0[ki]; b1.u = vfr1[ki];
                #pragma unroll
                for (int dd = 0; dd < 4; dd++){
                    union { uint4 u; f16x8 f; } a; a.u = af[kk*4+dd];
                    acc0[dd] = __builtin_amdgcn_mfma_f32_16x16x32_f16(a.f, b0.f, acc0[dd], 0, 0, 0);
                    acc1[dd] = __builtin_amdgcn_mfma_f32_16x16x32_f16(a.f, b1.f, acc1[dd], 0, 0, 0);
                }
            }
        }
        #pragma unroll
        for (int dd = 0; dd < 4; dd++){
            int dt = h*4 + dd;
            const f32x4 vg = *(const f32x4*)&vaL[dt*16 + q*4];
            ep0 += vg[0] * tanh_fast(acc0[dd][0]);
            ep0 += vg[1] * tanh_fast(acc0[dd][1]);
            ep0 += vg[2] * tanh_fast(acc0[dd][2]);
            ep0 += vg[3] * tanh_fast(acc0[dd][3]);
            ep1 += vg[0] * tanh_fast(acc1[dd][0]);
            ep1 += vg[1] * tanh_fast(acc1[dd][1]);
            ep1 += vg[2] * tanh_fast(acc1[dd][2]);
            ep1 += vg[3] * tanh_fast(acc1[dd][3]);
        }
    }
    ep0 += __shfl_xor(ep0, 16);
    ep0 += __shfl_xor(ep0, 32);          // e[tile0 col m], replicated over q
    ep1 += __shfl_xor(ep1, 16);
    ep1 += __shfl_xor(ep1, 32);

    // NO-MAX softmax weights (|e| << 88, f32-safe)
    float w0 = __expf(ep0);
    float w1 = __expf(ep1);
    float Sw = w0 + w1;

    // ---- pool from the lane's OWN V registers (after MFMA phase) ----
    float accp[32];                      // k = ki*32 + q*8 + t
    #pragma unroll
    for (int ki = 0; ki < 4; ki++){
        union { uint4 u; f16x2 h[4]; } v0, v1;
        v0.u = vfr0[ki]; v1.u = vfr1[ki];
        accp[ki*8 + 0] = w0 * (float)v0.h[0][0] + w1 * (float)v1.h[0][0];
        accp[ki*8 + 1] = w0 * (float)v0.h[0][1] + w1 * (float)v1.h[0][1];
        accp[ki*8 + 2] = w0 * (float)v0.h[1][0] + w1 * (float)v1.h[1][0];
        accp[ki*8 + 3] = w0 * (float)v0.h[1][1] + w1 * (float)v1.h[1][1];
        accp[ki*8 + 4] = w0 * (float)v0.h[2][0] + w1 * (float)v1.h[2][0];
        accp[ki*8 + 5] = w0 * (float)v0.h[2][1] + w1 * (float)v1.h[2][1];
        accp[ki*8 + 6] = w0 * (float)v0.h[3][0] + w1 * (float)v1.h[3][0];
        accp[ki*8 + 7] = w0 * (float)v0.h[3][1] + w1 * (float)v1.h[3][1];
    }

    // ---- reduce over the 16 m-lanes: fused v_add_f32_dpp (VALU, 1 inst/stage) ----
    #pragma unroll
    for (int j = 0; j < 32; j++){
        accp[j] = ROR_ADD(accp[j], "row_ror:1");
        accp[j] = ROR_ADD(accp[j], "row_ror:2");
        accp[j] = ROR_ADD(accp[j], "row_ror:4");
        accp[j] = ROR_ADD(accp[j], "row_ror:8");
    }
    Sw = ROR_ADD(Sw, "row_ror:1");
    Sw = ROR_ADD(Sw, "row_ror:2");
    Sw = ROR_ADD(Sw, "row_ror:4");
    Sw = ROR_ADD(Sw, "row_ror:8");

    size_t chunk = ((size_t)b*16 + x)*4 + w;      // 64 chunks per b, c = pos/32
    if (m == 0){
        float* pd = part + chunk*128;
        #pragma unroll
        for (int ki = 0; ki < 4; ki++){
            float4 lo = { accp[ki*8+0], accp[ki*8+1], accp[ki*8+2], accp[ki*8+3] };
            float4 hi = { accp[ki*8+4], accp[ki*8+5], accp[ki*8+6], accp[ki*8+7] };
            *(float4*)(pd + ki*32 + q*8)     = lo;   // 16B-aligned (elem%4==0)
            *(float4*)(pd + ki*32 + q*8 + 4) = hi;
        }
    }
    if (lane == 0)
        stats[chunk] = Sw;
}

// KB2: combine 64 chunk partials per b — common scale, pure sum/divide.
__global__ __launch_bounds__(128) void kb2_finish(const float* __restrict__ part,
        const float* __restrict__ stats, float* __restrict__ out)
{
    int b = blockIdx.x, d = threadIdx.x;
    const float* st = stats + (size_t)b*64;
    float S = 0.f;
    #pragma unroll 8
    for (int c = 0; c < 64; c++) S += st[c];
    const float* p = part + (size_t)b*64*128 + d;
    float s = 0.f;
    #pragma unroll 8
    for (int c = 0; c < 64; c++) s += p[c*128];
    out[b*128 + d] = s / S;
}

extern "C" void kernel_launch(void* const* d_in, const int* in_sizes, int n_in,
                              void* d_out, int out_size, void* d_ws, size_t ws_size,
                              hipStream_t stream)
{
    const int*   seq = (const int*)d_in[0];
    const float* emb = (const float*)d_in[1];
    const float* cw  = (const float*)d_in[2];
    const float* cb  = (const float*)d_in[3];
    const float* Wa  = (const float*)d_in[4];
    const float* va  = (const float*)d_in[5];
    float* out = (float*)d_out;

    char* wsb = (char*)d_ws;
    float*    part  = (float*)wsb;                         // 4 MiB (128*64*128 f32)
    float*    stats = (float*)(wsb + (8<<20));             // 32 KiB (128*64 f32)
    unsigned* tblG  = (unsigned*)(wsb + (12<<20));         // 6592 B (84B rows)
    unsigned* wahG  = (unsigned*)(wsb + (12<<20) + 32768); // 32 KiB (frag-ordered)

    k_setup   <<<5,            256, 0, stream>>>(emb, cw, cb, Wa, tblG, wahG);
    k_fused   <<<dim3(16,128), 256, 0, stream>>>(seq, tblG, wahG, va, part, stats);
    kb2_finish<<<128,          128, 0, stream>>>(part, stats, out);
}

// Round 12
// 93.958 us; speedup vs baseline: 1.1077x; 1.1077x over previous
//
#include <hip/hip_runtime.h>

#define LSEQ 8194

typedef _Float16 f16x8 __attribute__((ext_vector_type(8)));
typedef _Float16 f16x2 __attribute__((ext_vector_type(2)));
typedef __attribute__((ext_vector_type(4))) float f32x4;

static __device__ __forceinline__ float tanh_fast(float x){
    float p = __expf(2.0f * x);
    float r = __builtin_amdgcn_rcpf(1.0f + p);
    return 1.0f - 2.0f * r;
}
// sum 3 packed-f16x2 taps + relu (v_pk_add_f16 + v_pk_max_f16)
static __device__ __forceinline__ unsigned h3relu(unsigned a, unsigned b, unsigned c){
    union { f16x2 h; unsigned u; } x, y, z, r;
    x.u = a; y.u = b; z.u = c;
    f16x2 s = x.h + y.h + z.h;
    f16x2 zero = { (_Float16)0.0f, (_Float16)0.0f };
    r.h = __builtin_elementwise_max(s, zero);
    return r.u;
}
static __device__ __forceinline__ unsigned hpack(float a, float b){
    union { f16x2 h; unsigned u; } pk;
    pk.h = (f16x2){ (_Float16)a, (_Float16)b };
    return pk.u;
}
// x + row_ror(x): VALU DPP cross-lane add within a 16-lane row (NO LDS pipe).
// Builtin form (compiler schedules/hazard-handles it): R8/R9-proven.
#define ROR_ADD(x, ctrl) ({ \
    union { float f; int i; } _s, _r; _s.f = (x); \
    _r.i = __builtin_amdgcn_update_dpp(0, _s.i, (ctrl), 0xF, 0xF, true); \
    (x) + _r.f; })

// K_SETUP (R9-exact): tap table at stride 80B (16B-ALIGNED gathers: letter*80
// is 0 mod 16 — the stride-84 "conflict fix" of R10/R11 broke b128 alignment
// and regressed; conflicts were never on the critical path) + Wa f16 image in
// fragment order: uint4 (dt*4+ki)*64+lane = words (dt*16+m)*64+ki*16+q*4+j.
__global__ __launch_bounds__(256) void k_setup(
        const float* __restrict__ emb, const float* __restrict__ cw,
        const float* __restrict__ cb, const float* __restrict__ Wa,
        unsigned* __restrict__ tblG, unsigned* __restrict__ wahG)
{
    int gid = blockIdx.x*256 + threadIdx.x;
    if (gid < 1248){
        int k = gid / 416;          // 416 = 26*16
        int rem = gid - k*416;
        int l = rem >> 4;
        int cp = rem & 15;
        int c0 = cp*2;
        float v0 = 0.f, v1 = 0.f;
        #pragma unroll
        for (int i = 0; i < 5; i++){
            float e = emb[l*5 + i];
            v0 += cw[(c0*5 + i)*3 + k] * e;
            v1 += cw[((c0+1)*5 + i)*3 + k] * e;
        }
        if (k == 2){ v0 += cb[c0]; v1 += cb[c0+1]; }
        tblG[k*520 + l*20 + (cp & 3)*4 + (cp >> 2)] = hpack(v0, v1);
    }
    for (int u = gid; u < 2048; u += 1280){
        int lane = u & 63, dtki = u >> 6;
        int dt = dtki >> 2, ki = dtki & 3;
        int m = lane & 15, q = lane >> 4;
        const float2* src = (const float2*)Wa + ((dt*16 + m)*64 + ki*16 + q*4);
        float2 s0 = src[0], s1 = src[1], s2 = src[2], s3 = src[3];
        uint4 o;
        o.x = hpack(s0.x, s0.y);
        o.y = hpack(s1.x, s1.y);
        o.z = hpack(s2.x, s2.y);
        o.w = hpack(s3.x, s3.y);
        ((uint4*)wahG)[u] = o;
    }
}

// K_FUSED v13 = EXACT R9 (v10) revert — the best measured configuration
// (93.4us total). Ledger: math-level changes (paired tiles, DPP reduce,
// no-max softmax, Wa->L1 eviction) = 4 wins; schedule/asm micro-opts
// (manual dbuf x2, fused finish, stride-84, asm-DPP) = 5 losses, all via
// regalloc perturbation (VGPR-64/AGPR-shuffle signature) or alignment.
// hipcc's schedule is the asset here — do not hand-schedule this kernel.
__global__ __launch_bounds__(256, 2) void k_fused(
        const int* __restrict__ seq, const unsigned* __restrict__ tblG,
        const unsigned* __restrict__ wahG, const float* __restrict__ va,
        float* __restrict__ part, float* __restrict__ stats)
{
    __shared__ __align__(16) unsigned tblH[1560];      // 6240 B perm tap table
    __shared__ unsigned short seqw16[4][132];          // pre-scaled offsets (x80)
    __shared__ __align__(16) float vaL[128];

    int tid = threadIdx.x;
    int b   = blockIdx.y;
    int x   = blockIdx.x;
    int n0  = x * 128;

    // ---- prologue: small copies (one barrier) ----
    for (int i = tid; i < 390; i += 256)
        ((uint4*)tblH)[i] = ((const uint4*)tblG)[i];
    if (tid < 128) vaL[tid] = va[tid];
    const int* sb = seq + (size_t)b * LSEQ;
    for (int i = tid; i < 4*132; i += 256){
        int s = i / 132, off = i - s*132;
        if (off < 130)
            seqw16[s][off] = (unsigned short)(sb[s*2048 + n0 + off] * 80);
    }
    __syncthreads();   // the ONLY barrier

    int w = tid >> 6, lane = tid & 63;
    int m = lane & 15, q = lane >> 4;
    const char* tb0 = (const char*)tblH + q*16;
    const char* tb1 = tb0 + 2080;
    const char* tb2 = tb1 + 2080;
    const uint4* wa4 = (const uint4*)wahG + lane;      // lane-contiguous frags

    // ---- gen BOTH tiles' B-frags (V scratch dies per scope) ----
    uint4 vfr0[4], vfr1[4];
    {
        int base = w*32 + m;
        unsigned V[4][4];
        #pragma unroll
        for (int s = 0; s < 4; s++){
            unsigned oa = seqw16[s][base];
            unsigned ob = seqw16[s][base+1];
            unsigned oc = seqw16[s][base+2];
            uint4 t0 = *(const uint4*)(tb0 + oa);
            uint4 t1 = *(const uint4*)(tb1 + ob);
            uint4 t2 = *(const uint4*)(tb2 + oc);
            V[s][0] = h3relu(t0.x, t1.x, t2.x);
            V[s][1] = h3relu(t0.y, t1.y, t2.y);
            V[s][2] = h3relu(t0.z, t1.z, t2.z);
            V[s][3] = h3relu(t0.w, t1.w, t2.w);
        }
        #pragma unroll
        for (int ki = 0; ki < 4; ki++){
            uint4 o;
            o.x = __builtin_amdgcn_perm(V[1][ki], V[0][ki], 0x05040100u);
            o.y = __builtin_amdgcn_perm(V[3][ki], V[2][ki], 0x05040100u);
            o.z = __builtin_amdgcn_perm(V[1][ki], V[0][ki], 0x07060302u);
            o.w = __builtin_amdgcn_perm(V[3][ki], V[2][ki], 0x07060302u);
            vfr0[ki] = o;
        }
    }
    {
        int base = w*32 + 16 + m;
        unsigned V[4][4];
        #pragma unroll
        for (int s = 0; s < 4; s++){
            unsigned oa = seqw16[s][base];
            unsigned ob = seqw16[s][base+1];
            unsigned oc = seqw16[s][base+2];
            uint4 t0 = *(const uint4*)(tb0 + oa);
            uint4 t1 = *(const uint4*)(tb1 + ob);
            uint4 t2 = *(const uint4*)(tb2 + oc);
            V[s][0] = h3relu(t0.x, t1.x, t2.x);
            V[s][1] = h3relu(t0.y, t1.y, t2.y);
            V[s][2] = h3relu(t0.z, t1.z, t2.z);
            V[s][3] = h3relu(t0.w, t1.w, t2.w);
        }
        #pragma unroll
        for (int ki = 0; ki < 4; ki++){
            uint4 o;
            o.x = __builtin_amdgcn_perm(V[1][ki], V[0][ki], 0x05040100u);
            o.y = __builtin_amdgcn_perm(V[3][ki], V[2][ki], 0x05040100u);
            o.z = __builtin_amdgcn_perm(V[1][ki], V[0][ki], 0x07060302u);
            o.w = __builtin_amdgcn_perm(V[3][ki], V[2][ki], 0x07060302u);
            vfr1[ki] = o;
        }
    }

    // ---- MFMA: 2 halves x 2 ki-pairs; per batch 8 coalesced A-loads feed
    //      16 MFMAs (both tiles). acc accumulation order stays ki-ascending.
    float ep0 = 0.f, ep1 = 0.f;
    #pragma unroll
    for (int h = 0; h < 2; h++){
        f32x4 acc0[4], acc1[4];
        #pragma unroll
        for (int dd = 0; dd < 4; dd++){
            acc0[dd] = (f32x4){0.f, 0.f, 0.f, 0.f};
            acc1[dd] = (f32x4){0.f, 0.f, 0.f, 0.f};
        }
        #pragma unroll
        for (int kp = 0; kp < 2; kp++){
            uint4 af[8];                 // [kk*4+dd], kk = ki-kp*2
            #pragma unroll
            for (int kk = 0; kk < 2; kk++)
                #pragma unroll
                for (int dd = 0; dd < 4; dd++){
                    int dt = h*4 + dd, ki = kp*2 + kk;
                    af[kk*4+dd] = wa4[(dt*4 + ki) << 6];
                }
            #pragma unroll
            for (int kk = 0; kk < 2; kk++){
                int ki = kp*2 + kk;
                union { uint4 u; f16x8 f; } b0, b1;
                b0.u = vfr0[ki]; b1.u = vfr1[ki];
                #pragma unroll
                for (int dd = 0; dd < 4; dd++){
                    union { uint4 u; f16x8 f; } a; a.u = af[kk*4+dd];
                    acc0[dd] = __builtin_amdgcn_mfma_f32_16x16x32_f16(a.f, b0.f, acc0[dd], 0, 0, 0);
                    acc1[dd] = __builtin_amdgcn_mfma_f32_16x16x32_f16(a.f, b1.f, acc1[dd], 0, 0, 0);
                }
            }
        }
        #pragma unroll
        for (int dd = 0; dd < 4; dd++){
            int dt = h*4 + dd;
            const f32x4 vg = *(const f32x4*)&vaL[dt*16 + q*4];
            ep0 += vg[0] * tanh_fast(acc0[dd][0]);
            ep0 += vg[1] * tanh_fast(acc0[dd][1]);
            ep0 += vg[2] * tanh_fast(acc0[dd][2]);
            ep0 += vg[3] * tanh_fast(acc0[dd][3]);
            ep1 += vg[0] * tanh_fast(acc1[dd][0]);
            ep1 += vg[1] * tanh_fast(acc1[dd][1]);
            ep1 += vg[2] * tanh_fast(acc1[dd][2]);
            ep1 += vg[3] * tanh_fast(acc1[dd][3]);
        }
    }
    ep0 += __shfl_xor(ep0, 16);
    ep0 += __shfl_xor(ep0, 32);          // e[tile0 col m], replicated over q
    ep1 += __shfl_xor(ep1, 16);
    ep1 += __shfl_xor(ep1, 32);

    // NO-MAX softmax weights (|e| << 88, f32-safe)
    float w0 = __expf(ep0);
    float w1 = __expf(ep1);
    float Sw = w0 + w1;

    // ---- pool from the lane's OWN V registers (after MFMA phase) ----
    float accp[32];                      // k = ki*32 + q*8 + t
    #pragma unroll
    for (int ki = 0; ki < 4; ki++){
        union { uint4 u; f16x2 h[4]; } v0, v1;
        v0.u = vfr0[ki]; v1.u = vfr1[ki];
        accp[ki*8 + 0] = w0 * (float)v0.h[0][0] + w1 * (float)v1.h[0][0];
        accp[ki*8 + 1] = w0 * (float)v0.h[0][1] + w1 * (float)v1.h[0][1];
        accp[ki*8 + 2] = w0 * (float)v0.h[1][0] + w1 * (float)v1.h[1][0];
        accp[ki*8 + 3] = w0 * (float)v0.h[1][1] + w1 * (float)v1.h[1][1];
        accp[ki*8 + 4] = w0 * (float)v0.h[2][0] + w1 * (float)v1.h[2][0];
        accp[ki*8 + 5] = w0 * (float)v0.h[2][1] + w1 * (float)v1.h[2][1];
        accp[ki*8 + 6] = w0 * (float)v0.h[3][0] + w1 * (float)v1.h[3][0];
        accp[ki*8 + 7] = w0 * (float)v0.h[3][1] + w1 * (float)v1.h[3][1];
    }

    // ---- reduce over the 16 m-lanes via DPP row_ror (VALU, no LDS pipe) ----
    #pragma unroll
    for (int j = 0; j < 32; j++){
        accp[j] = ROR_ADD(accp[j], 0x121);   // ror1
        accp[j] = ROR_ADD(accp[j], 0x122);   // ror2
        accp[j] = ROR_ADD(accp[j], 0x124);   // ror4
        accp[j] = ROR_ADD(accp[j], 0x128);   // ror8
    }
    Sw = ROR_ADD(Sw, 0x121);
    Sw = ROR_ADD(Sw, 0x122);
    Sw = ROR_ADD(Sw, 0x124);
    Sw = ROR_ADD(Sw, 0x128);

    size_t chunk = ((size_t)b*16 + x)*4 + w;      // 64 chunks per b, c = pos/32
    if (m == 0){
        float* pd = part + chunk*128;
        #pragma unroll
        for (int ki = 0; ki < 4; ki++){
            float4 lo = { accp[ki*8+0], accp[ki*8+1], accp[ki*8+2], accp[ki*8+3] };
            float4 hi = { accp[ki*8+4], accp[ki*8+5], accp[ki*8+6], accp[ki*8+7] };
            *(float4*)(pd + ki*32 + q*8)     = lo;   // 16B-aligned (elem%4==0)
            *(float4*)(pd + ki*32 + q*8 + 4) = hi;
        }
    }
    if (lane == 0)
        stats[chunk] = Sw;
}

// KB2: combine 64 chunk partials per b — common scale, pure sum/divide.
__global__ __launch_bounds__(128) void kb2_finish(const float* __restrict__ part,
        const float* __restrict__ stats, float* __restrict__ out)
{
    int b = blockIdx.x, d = threadIdx.x;
    const float* st = stats + (size_t)b*64;
    float S = 0.f;
    #pragma unroll 8
    for (int c = 0; c < 64; c++) S += st[c];
    const float* p = part + (size_t)b*64*128 + d;
    float s = 0.f;
    #pragma unroll 8
    for (int c = 0; c < 64; c++) s += p[c*128];
    out[b*128 + d] = s / S;
}

extern "C" void kernel_launch(void* const* d_in, const int* in_sizes, int n_in,
                              void* d_out, int out_size, void* d_ws, size_t ws_size,
                              hipStream_t stream)
{
    const int*   seq = (const int*)d_in[0];
    const float* emb = (const float*)d_in[1];
    const float* cw  = (const float*)d_in[2];
    const float* cb  = (const float*)d_in[3];
    const float* Wa  = (const float*)d_in[4];
    const float* va  = (const float*)d_in[5];
    float* out = (float*)d_out;

    char* wsb = (char*)d_ws;
    float*    part  = (float*)wsb;                         // 4 MiB (128*64*128 f32)
    float*    stats = (float*)(wsb + (8<<20));             // 32 KiB (128*64 f32)
    unsigned* tblG  = (unsigned*)(wsb + (12<<20));         // 6240 B
    unsigned* wahG  = (unsigned*)(wsb + (12<<20) + 32768); // 32 KiB (frag-ordered)

    k_setup   <<<5,            256, 0, stream>>>(emb, cw, cb, Wa, tblG, wahG);
    k_fused   <<<dim3(16,128), 256, 0, stream>>>(seq, tblG, wahG, va, part, stats);
    kb2_finish<<<128,          128, 0, stream>>>(part, stats, out);
}